// Round 1
// baseline (519.673 us; speedup 1.0000x reference)
//
#include <hip/hip_runtime.h>

// GRU, B=16384 rows, T=4096 steps, H=1 (scalar recurrence per row), fp32.
// One thread per row; 256 blocks x 64 threads -> 1 wave per CU across all
// 256 CUs. Latency-bound on the serial h->r->n->h' chain (~50 cyc/step).
// x streamed via register double-buffer (2 x 8 float4 per thread).

#define LOG2E 1.4426950408889634f
#define T_LEN 4096
#define B_ROWS 16384

__device__ __forceinline__ float fast_exp2(float x) {
    return __builtin_amdgcn_exp2f(x);
}
__device__ __forceinline__ float fast_rcp(float x) {
    return __builtin_amdgcn_rcpf(x);
}

// One GRU timestep on scalar h given input x-value xv.
// Constants pre-scaled:
//   ar1 = -log2e*wih_r, ar0 = -log2e*(bih_r+bhh_r), Ar = -log2e*whh_r
//   az* likewise for z
//   an1 = 2log2e*wih_n, an0 = 2log2e*bih_n, An = 2log2e*whh_n, Bn = 2log2e*bhh_n
// r = sigmoid(gx_r+gh_r) = 1/(1+exp2(fma(h,Ar,fma(xv,ar1,ar0))))
// n = tanh(y), y = gx_n + r*gh_n ; tanh(y) = 1 - 2q, q = 1/(1+exp2(2log2e*y))
// h' = n + z*(h-n) = fma(z, (h-1)+2q, 1-2q)
#define GRU_STEP(h, xv)                                                     \
    do {                                                                    \
        float Cr = __builtin_fmaf((xv), ar1, ar0);                          \
        float Cz = __builtin_fmaf((xv), az1, az0);                          \
        float Cn = __builtin_fmaf((xv), an1, an0);                          \
        float uR = __builtin_fmaf((h), Ar, Cr);                             \
        float uZ = __builtin_fmaf((h), Az, Cz);                             \
        float Gn = __builtin_fmaf((h), An, Bn);                             \
        float eR = fast_exp2(uR);                                           \
        float eZ = fast_exp2(uZ);                                           \
        float r  = fast_rcp(1.0f + eR);                                     \
        float z  = fast_rcp(1.0f + eZ);                                     \
        float v  = __builtin_fmaf(r, Gn, Cn);                               \
        float e2 = fast_exp2(v);                                            \
        float q  = fast_rcp(1.0f + e2);                                     \
        float hm1 = (h) - 1.0f;                                             \
        float t1  = __builtin_fmaf(2.0f, q, hm1);                           \
        float nn  = __builtin_fmaf(-2.0f, q, 1.0f);                         \
        (h) = __builtin_fmaf(z, t1, nn);                                    \
    } while (0)

__global__ __launch_bounds__(64, 1)
void gru_scan_kernel(const float* __restrict__ x,
                     const float* __restrict__ w_ih,
                     const float* __restrict__ w_hh,
                     const float* __restrict__ b_ih,
                     const float* __restrict__ b_hh,
                     const float* __restrict__ fc_w,
                     const float* __restrict__ fc_b,
                     float* __restrict__ out)
{
    const int row = blockIdx.x * 64 + threadIdx.x;

    // Wave-uniform weight scalars (gate order: r, z, n).
    const float wr = w_ih[0], wz = w_ih[1], wn = w_ih[2];
    const float vr = w_hh[0], vz = w_hh[1], vn = w_hh[2];
    const float br = b_ih[0], bz = b_ih[1], bn = b_ih[2];
    const float cr = b_hh[0], cz = b_hh[1], cn = b_hh[2];

    const float ar1 = -LOG2E * wr, ar0 = -LOG2E * (br + cr), Ar = -LOG2E * vr;
    const float az1 = -LOG2E * wz, az0 = -LOG2E * (bz + cz), Az = -LOG2E * vz;
    const float an1 = 2.0f * LOG2E * wn, an0 = 2.0f * LOG2E * bn;
    const float An  = 2.0f * LOG2E * vn, Bn  = 2.0f * LOG2E * cn;

    const float fcw = fc_w[0], fcb = fc_b[0];

    const float4* xr = (const float4*)(x + (size_t)row * T_LEN);

    // Register double-buffer: tiles of 32 timesteps (8 x float4).
    float4 A[8], Bv[8];
#pragma unroll
    for (int k = 0; k < 8; ++k) A[k] = xr[k];

    float h = 0.0f;

#pragma unroll 1
    for (int tb = 0; tb < 128; tb += 2) {
        // Prefetch tile tb+1 into Bv while computing tile tb from A.
        const float4* pB = xr + (tb + 1) * 8;
#pragma unroll
        for (int k = 0; k < 8; ++k) Bv[k] = pB[k];

#pragma unroll
        for (int k = 0; k < 8; ++k) {
            float4 xv = A[k];
            GRU_STEP(h, xv.x);
            GRU_STEP(h, xv.y);
            GRU_STEP(h, xv.z);
            GRU_STEP(h, xv.w);
        }

        // Prefetch tile tb+2 into A (wrap to 0 on the last pair: harmless
        // in-bounds re-read, keeps the loop branch-free).
        const float4* pA = xr + ((tb + 2) & 127) * 8;
#pragma unroll
        for (int k = 0; k < 8; ++k) A[k] = pA[k];

#pragma unroll
        for (int k = 0; k < 8; ++k) {
            float4 xv = Bv[k];
            GRU_STEP(h, xv.x);
            GRU_STEP(h, xv.y);
            GRU_STEP(h, xv.z);
            GRU_STEP(h, xv.w);
        }
    }

    out[row] = __builtin_fmaf(h, fcw, fcb);
}

extern "C" void kernel_launch(void* const* d_in, const int* in_sizes, int n_in,
                              void* d_out, int out_size, void* d_ws, size_t ws_size,
                              hipStream_t stream)
{
    const float* x    = (const float*)d_in[0];
    const float* w_ih = (const float*)d_in[1];
    const float* w_hh = (const float*)d_in[2];
    const float* b_ih = (const float*)d_in[3];
    const float* b_hh = (const float*)d_in[4];
    const float* fc_w = (const float*)d_in[5];
    const float* fc_b = (const float*)d_in[6];
    float* out = (float*)d_out;

    gru_scan_kernel<<<B_ROWS / 64, 64, 0, stream>>>(
        x, w_ih, w_hh, b_ih, b_hh, fc_w, fc_b, out);
}